// Round 5
// baseline (151.758 us; speedup 1.0000x reference)
//
#include <hip/hip_runtime.h>

typedef short bf16x8 __attribute__((ext_vector_type(8)));
typedef float f32x4 __attribute__((ext_vector_type(4)));
typedef unsigned short u16;
typedef unsigned int u32;

#define MFMA_BF16 __builtin_amdgcn_mfma_f32_16x16x32_bf16

static __device__ __forceinline__ u16 f2bf(float f) {
  union { float f; unsigned u; } v; v.f = f;
  return (u16)((v.u + 0x7FFFu + ((v.u >> 16) & 1u)) >> 16);  // RNE
}
static __device__ __forceinline__ u32 pack2bf(float a, float b) {
  return (u32)f2bf(a) | ((u32)f2bf(b) << 16);
}
static __device__ __forceinline__ short cvbf(u32 u) {
  union { u32 u; float f; } v; v.u = u;
  return (short)f2bf(v.f);
}

// ---------------- Kernel 0: W -> Wt[192][1024] bf16; Q gets 1/sqrt(64)*log2(e) folded in
__global__ __launch_bounds__(256) void wt_kernel(const float* __restrict__ Wq,
                                                 const float* __restrict__ Wk,
                                                 const float* __restrict__ Wv,
                                                 u16* __restrict__ Wt) {
  const int nrow = blockIdx.x;               // 0..191
  const int m = nrow >> 6, n = nrow & 63;
  const float* W = (m == 0) ? Wq : ((m == 1) ? Wk : Wv);
  const float s = (m == 0) ? 0.125f * 1.44269504f : 1.0f;  // scores in base-2 units
  for (int k = threadIdx.x; k < 1024; k += 256)
    Wt[(size_t)nrow * 1024 + k] = f2bf(W[(size_t)k * 64 + n] * s);
}

// ---------------- Kernel 1: QKV projection, x read once, EXPLICIT 2-deep reg pipeline.
// 1024 blocks x 16 rows; wave w computes n-subtiles {3w..3w+2} of 12
// (Q:0-3, K:4-7, V:8-11; V stored transposed). K-step = 64.
__global__ __launch_bounds__(256) void qkv4(const float* __restrict__ x,
                                            const u16* __restrict__ Wt,
                                            u16* __restrict__ Qb,
                                            u16* __restrict__ Kb,
                                            u16* __restrict__ Vt) {
  const int w = threadIdx.x >> 6, l = threadIdx.x & 63;
  const int lane16 = l & 15, laneHi = l >> 4;
  const int r0 = blockIdx.x * 16;
  const int nt0 = w * 3;
  const float* xrow = x + (size_t)(r0 + lane16) * 1024 + 8 * laneHi;
  const u16* w0 = Wt + (size_t)((nt0 + 0) * 16 + lane16) * 1024 + 8 * laneHi;
  const u16* w1 = Wt + (size_t)((nt0 + 1) * 16 + lane16) * 1024 + 8 * laneHi;
  const u16* w2 = Wt + (size_t)((nt0 + 2) * 16 + lane16) * 1024 + 8 * laneHi;

  const f32x4 fzero = {0.f, 0.f, 0.f, 0.f};
  f32x4 acc[3] = {fzero, fzero, fzero};

  uint4 xa0, xa1, xa2, xa3, xb0, xb1, xb2, xb3;      // A fp32 frags (2 halves x 32B)
  bf16x8 ba0, ba1, ba2, ba3, ba4, ba5;               // B frags: subtile i, half h
  bf16x8 bb0, bb1, bb2, bb3, bb4, bb5;

#define QLOAD(X0, X1, X2, X3, B0, B1, B2, B3, B4, B5, s)        \
  {                                                             \
    const int c = (s) * 64;                                     \
    X0 = *(const uint4*)(xrow + c);                             \
    X1 = *(const uint4*)(xrow + c + 4);                         \
    X2 = *(const uint4*)(xrow + c + 32);                        \
    X3 = *(const uint4*)(xrow + c + 36);                        \
    B0 = *(const bf16x8*)(w0 + c);                              \
    B1 = *(const bf16x8*)(w0 + c + 32);                         \
    B2 = *(const bf16x8*)(w1 + c);                              \
    B3 = *(const bf16x8*)(w1 + c + 32);                         \
    B4 = *(const bf16x8*)(w2 + c);                              \
    B5 = *(const bf16x8*)(w2 + c + 32);                         \
  }

#define QCOMP(X0, X1, X2, X3, B0, B1, B2, B3, B4, B5)           \
  {                                                             \
    bf16x8 a0, a1;                                              \
    a0[0] = cvbf(X0.x); a0[1] = cvbf(X0.y); a0[2] = cvbf(X0.z); a0[3] = cvbf(X0.w); \
    a0[4] = cvbf(X1.x); a0[5] = cvbf(X1.y); a0[6] = cvbf(X1.z); a0[7] = cvbf(X1.w); \
    a1[0] = cvbf(X2.x); a1[1] = cvbf(X2.y); a1[2] = cvbf(X2.z); a1[3] = cvbf(X2.w); \
    a1[4] = cvbf(X3.x); a1[5] = cvbf(X3.y); a1[6] = cvbf(X3.z); a1[7] = cvbf(X3.w); \
    acc[0] = MFMA_BF16(a0, B0, acc[0], 0, 0, 0);                \
    acc[0] = MFMA_BF16(a1, B1, acc[0], 0, 0, 0);                \
    acc[1] = MFMA_BF16(a0, B2, acc[1], 0, 0, 0);                \
    acc[1] = MFMA_BF16(a1, B3, acc[1], 0, 0, 0);                \
    acc[2] = MFMA_BF16(a0, B4, acc[2], 0, 0, 0);                \
    acc[2] = MFMA_BF16(a1, B5, acc[2], 0, 0, 0);                \
  }

  QLOAD(xa0, xa1, xa2, xa3, ba0, ba1, ba2, ba3, ba4, ba5, 0)
#pragma unroll
  for (int s = 0; s < 16; s += 2) {
    if (s + 1 < 16) QLOAD(xb0, xb1, xb2, xb3, bb0, bb1, bb2, bb3, bb4, bb5, s + 1)
    QCOMP(xa0, xa1, xa2, xa3, ba0, ba1, ba2, ba3, ba4, ba5)
    if (s + 2 < 16) QLOAD(xa0, xa1, xa2, xa3, ba0, ba1, ba2, ba3, ba4, ba5, s + 2)
    QCOMP(xb0, xb1, xb2, xb3, bb0, bb1, bb2, bb3, bb4, bb5)
  }

#pragma unroll
  for (int i = 0; i < 3; ++i) {
    const int nt = nt0 + i;
    if (nt < 4) {
#pragma unroll
      for (int r = 0; r < 4; ++r)
        Qb[(size_t)(r0 + laneHi * 4 + r) * 64 + nt * 16 + lane16] = f2bf(acc[i][r]);
    } else if (nt < 8) {
#pragma unroll
      for (int r = 0; r < 4; ++r)
        Kb[(size_t)(r0 + laneHi * 4 + r) * 64 + (nt - 4) * 16 + lane16] = f2bf(acc[i][r]);
    } else {
      const int d = (nt - 8) * 16 + lane16;
      uint2 v;
      v.x = pack2bf(acc[i][0], acc[i][1]);
      v.y = pack2bf(acc[i][2], acc[i][3]);
      *(uint2*)(Vt + (size_t)d * 16384 + r0 + laneHi * 4) = v;
    }
  }
}

// ---------------- Kernel 2: causal flash attention, register-direct K/V.
// Balanced q-tile map; 4 waves split causal KV range; LDS combine; setprio on MFMA.
#define PLD 72

__global__ __launch_bounds__(256) void attn3(const u16* __restrict__ Qb,
                                             const u16* __restrict__ Kb,
                                             const u16* __restrict__ Vt,
                                             float* __restrict__ out) {
  __shared__ __align__(16) u16 shP[4][16 * PLD];   // per-wave P scratch
  __shared__ float shC[3][64][24];                 // waves 1..3 partials

  const int tid = threadIdx.x, w = tid >> 6, l = tid & 63;
  const int lane16 = l & 15, laneHi = l >> 4;
  const int b = blockIdx.x & 3;
  const int j = blockIdx.x >> 2;
  const int g = j >> 6, r_ = j & 63;
  const int t = (g == 0) ? (255 - r_) : (g == 1) ? r_ : (g == 2) ? (191 - r_) : (64 + r_);
  const int q0 = t * 16, bT = b * 4096;

  const u16* qrow = Qb + (size_t)(bT + q0 + lane16) * 64;
  const bf16x8 qf0 = *(const bf16x8*)(qrow + 8 * laneHi);
  const bf16x8 qf1 = *(const bf16x8*)(qrow + 32 + 8 * laneHi);

  const int n64 = (t + 4) >> 2;                    // ceil((t+1)/4) 64-key units
  const int s = (n64 * w) >> 2, e = (n64 * (w + 1)) >> 2;

  const f32x4 fzero = {0.f, 0.f, 0.f, 0.f};
  f32x4 o[4] = {fzero, fzero, fzero, fzero};
  float mrow[4] = {-INFINITY, -INFINITY, -INFINITY, -INFINITY};
  float lrow[4] = {0.f, 0.f, 0.f, 0.f};

  bf16x8 kA[8], vA[8], kB[8], vB[8];

  auto loadKV = [&](bf16x8 (&kf)[8], bf16x8 (&vf)[8], int u) {
    const int k0 = bT + u * 64;
#pragma unroll
    for (int i = 0; i < 4; ++i) {
      const u16* kp = Kb + (size_t)(k0 + i * 16 + lane16) * 64 + 8 * laneHi;
      kf[i * 2 + 0] = *(const bf16x8*)(kp);
      kf[i * 2 + 1] = *(const bf16x8*)(kp + 32);
      const u16* vp = Vt + (size_t)(i * 16 + lane16) * 16384 + k0 + 8 * laneHi;
      vf[i * 2 + 0] = *(const bf16x8*)(vp);
      vf[i * 2 + 1] = *(const bf16x8*)(vp + 32);
    }
  };

  auto compute = [&](bf16x8 (&kf)[8], bf16x8 (&vf)[8], int u) {
    f32x4 sc[4];
    __builtin_amdgcn_s_setprio(1);
#pragma unroll
    for (int ct = 0; ct < 4; ++ct) {
      f32x4 a = fzero;
      a = MFMA_BF16(qf0, kf[ct * 2 + 0], a, 0, 0, 0);
      a = MFMA_BF16(qf1, kf[ct * 2 + 1], a, 0, 0, 0);
      sc[ct] = a;
    }
    __builtin_amdgcn_s_setprio(0);
    if (u == n64 - 1) {                            // diagonal unit: causal mask
#pragma unroll
      for (int ct = 0; ct < 4; ++ct)
#pragma unroll
        for (int r = 0; r < 4; ++r) {
          const int col = u * 64 + ct * 16 + lane16;
          const int row = q0 + laneHi * 4 + r;
          if (col > row) sc[ct][r] = -INFINITY;
        }
    }
    float mt[4] = {-INFINITY, -INFINITY, -INFINITY, -INFINITY};
#pragma unroll
    for (int ct = 0; ct < 4; ++ct)
#pragma unroll
      for (int r = 0; r < 4; ++r) mt[r] = fmaxf(mt[r], sc[ct][r]);
#pragma unroll
    for (int d = 1; d < 16; d <<= 1)
#pragma unroll
      for (int r = 0; r < 4; ++r) mt[r] = fmaxf(mt[r], __shfl_xor(mt[r], d));

    float alpha[4], rs[4];
#pragma unroll
    for (int r = 0; r < 4; ++r) {
      const float mn = fmaxf(mrow[r], mt[r]);
      alpha[r] = exp2f(mrow[r] - mn);              // base-2 throughout
      mrow[r] = mn;
      rs[r] = 0.f;
    }
#pragma unroll
    for (int ct = 0; ct < 4; ++ct)
#pragma unroll
      for (int r = 0; r < 4; ++r) {
        const float pv = exp2f(sc[ct][r] - mrow[r]);
        rs[r] += pv;
        shP[w][(laneHi * 4 + r) * PLD + ct * 16 + lane16] = f2bf(pv);
      }
#pragma unroll
    for (int d = 1; d < 16; d <<= 1)
#pragma unroll
      for (int r = 0; r < 4; ++r) rs[r] += __shfl_xor(rs[r], d);
#pragma unroll
    for (int r = 0; r < 4; ++r) lrow[r] = lrow[r] * alpha[r] + rs[r];
#pragma unroll
    for (int nt = 0; nt < 4; ++nt)
#pragma unroll
      for (int r = 0; r < 4; ++r) o[nt][r] *= alpha[r];

    asm volatile("s_waitcnt lgkmcnt(0)" ::: "memory");  // wave-local P round-trip

    __builtin_amdgcn_s_setprio(1);
#pragma unroll
    for (int kk = 0; kk < 2; ++kk) {
      bf16x8 pa = *(const bf16x8*)&shP[w][lane16 * PLD + kk * 32 + 8 * laneHi];
#pragma unroll
      for (int nt = 0; nt < 4; ++nt)
        o[nt] = MFMA_BF16(pa, vf[nt * 2 + kk], o[nt], 0, 0, 0);
    }
    __builtin_amdgcn_s_setprio(0);
  };

  // main loop: 2x unrolled with double-buffered K/V fragment registers
  int u = s;
  if (u < e) loadKV(kA, vA, u);
  while (u < e) {
    if (u + 1 < e) loadKV(kB, vB, u + 1);
    compute(kA, vA, u);
    ++u;
    if (u >= e) break;
    if (u + 1 < e) loadKV(kA, vA, u + 1);
    compute(kB, vB, u);
    ++u;
  }

  // combine: waves 1..3 publish partials, wave 0 merges + writes out
  if (w > 0) {
    float* dst = &shC[w - 1][l][0];
#pragma unroll
    for (int r = 0; r < 4; ++r) { dst[r] = mrow[r]; dst[4 + r] = lrow[r]; }
#pragma unroll
    for (int nt = 0; nt < 4; ++nt)
#pragma unroll
      for (int r = 0; r < 4; ++r) dst[8 + nt * 4 + r] = o[nt][r];
  }
  __syncthreads();
  if (w == 0) {
#pragma unroll
    for (int peer = 0; peer < 3; ++peer) {
      const float* src = &shC[peer][l][0];
#pragma unroll
      for (int r = 0; r < 4; ++r) {
        const float pm = src[r], pl = src[4 + r];
        const float mn = fmaxf(mrow[r], pm);
        // fmaxf(NaN, -80) -> -80 : branchless guard for empty partials
        const float aS = exp2f(fmaxf(mrow[r] - mn, -80.f));
        const float aP = exp2f(fmaxf(pm - mn, -80.f));
        mrow[r] = mn;
        lrow[r] = lrow[r] * aS + pl * aP;
#pragma unroll
        for (int nt = 0; nt < 4; ++nt)
          o[nt][r] = o[nt][r] * aS + src[8 + nt * 4 + r] * aP;
      }
    }
    float inv[4];
#pragma unroll
    for (int r = 0; r < 4; ++r) inv[r] = 1.0f / lrow[r];
#pragma unroll
    for (int nt = 0; nt < 4; ++nt)
#pragma unroll
      for (int r = 0; r < 4; ++r)
        out[(size_t)(bT + q0 + laneHi * 4 + r) * 64 + nt * 16 + lane16] = o[nt][r] * inv[r];
  }
}

extern "C" void kernel_launch(void* const* d_in, const int* in_sizes, int n_in,
                              void* d_out, int out_size, void* d_ws, size_t ws_size,
                              hipStream_t stream) {
  const float* x  = (const float*)d_in[0];
  const float* Wq = (const float*)d_in[1];
  const float* Wk = (const float*)d_in[2];
  const float* Wv = (const float*)d_in[3];
  float* out = (float*)d_out;

  char* ws = (char*)d_ws;
  u16* Wt = (u16*)ws;                                   // 192*1024*2   = 384 KiB
  u16* Qb = (u16*)(ws + 393216);                        // 16384*64*2   = 2 MiB
  u16* Kb = (u16*)(ws + 393216 + 2097152);
  u16* Vt = (u16*)(ws + 393216 + 2 * 2097152);          // transposed V [64][16384]

  wt_kernel<<<192, 256, 0, stream>>>(Wq, Wk, Wv, Wt);
  qkv4<<<1024, 256, 0, stream>>>(x, Wt, Qb, Kb, Vt);
  attn3<<<1024, 256, 0, stream>>>(Qb, Kb, Vt, out);
}

// Round 7
// 131.962 us; speedup vs baseline: 1.1500x; 1.1500x over previous
//
#include <hip/hip_runtime.h>

typedef short bf16x8 __attribute__((ext_vector_type(8)));
typedef float f32x4 __attribute__((ext_vector_type(4)));
typedef unsigned short u16;
typedef unsigned int u32;

#define MFMA_BF16 __builtin_amdgcn_mfma_f32_16x16x32_bf16

static __device__ __forceinline__ u16 f2bf(float f) {
  union { float f; unsigned u; } v; v.f = f;
  return (u16)((v.u + 0x7FFFu + ((v.u >> 16) & 1u)) >> 16);  // RNE
}
static __device__ __forceinline__ u32 cvtpk(float lo, float hi) {
  u32 r;
  asm("v_cvt_pk_bf16_f32 %0, %1, %2" : "=v"(r) : "v"(lo), "v"(hi));
  return r;  // lo -> bits[15:0], hi -> bits[31:16]
}
static __device__ __forceinline__ bf16x8 cvt8(uint4 p, uint4 q) {  // 8 fp32 (raw bits) -> bf16x8
  union { u32 w[4]; bf16x8 b; } r;
  r.w[0] = cvtpk(__uint_as_float(p.x), __uint_as_float(p.y));
  r.w[1] = cvtpk(__uint_as_float(p.z), __uint_as_float(p.w));
  r.w[2] = cvtpk(__uint_as_float(q.x), __uint_as_float(q.y));
  r.w[3] = cvtpk(__uint_as_float(q.z), __uint_as_float(q.w));
  return r.b;
}

// ---------------- Kernel 0: W -> Wt[192][1024] bf16; Q gets 1/sqrt(64)*log2(e) folded in
__global__ __launch_bounds__(256) void wt_kernel(const float* __restrict__ Wq,
                                                 const float* __restrict__ Wk,
                                                 const float* __restrict__ Wv,
                                                 u16* __restrict__ Wt) {
  const int nrow = blockIdx.x;               // 0..191
  const int m = nrow >> 6, n = nrow & 63;
  const float* W = (m == 0) ? Wq : ((m == 1) ? Wk : Wv);
  const float s = (m == 0) ? 0.125f * 1.44269504f : 1.0f;  // scores in base-2 units
  for (int k = threadIdx.x; k < 1024; k += 256)
    Wt[(size_t)nrow * 1024 + k] = f2bf(W[(size_t)k * 64 + n] * s);
}

// ---------------- Kernel 1: QKV projection, pipelined register-direct GEMM.
// 512 blocks x 32 rows. All 4 waves read the SAME 32 x-rows (L1 hits); wave w
// computes n-subtiles {3w..3w+2} of 12 (Q:0-3, K:4-7, V:8-11 transposed).
// Runtime k-loop (#pragma unroll 1) + sched_barrier(0) pins the 2-deep pipeline.
__global__ __launch_bounds__(256) void qkv5(const float* __restrict__ x,
                                            const u16* __restrict__ Wt,
                                            u16* __restrict__ Qb,
                                            u16* __restrict__ Kb,
                                            u16* __restrict__ Vt) {
  const int w = threadIdx.x >> 6, l = threadIdx.x & 63;
  const int lane16 = l & 15, laneHi = l >> 4;
  const int r0 = blockIdx.x * 32;
  const int nt0 = w * 3;
  const float* x0 = x + (size_t)(r0 + lane16) * 1024 + 8 * laneHi;      // M-frag 0
  const float* x1 = x0 + 16 * 1024;                                     // M-frag 1
  const u16* w0 = Wt + (size_t)((nt0 + 0) * 16 + lane16) * 1024 + 8 * laneHi;
  const u16* w1 = Wt + (size_t)((nt0 + 1) * 16 + lane16) * 1024 + 8 * laneHi;
  const u16* w2 = Wt + (size_t)((nt0 + 2) * 16 + lane16) * 1024 + 8 * laneHi;

  const f32x4 fzero = {0.f, 0.f, 0.f, 0.f};
  f32x4 acc0 = fzero, acc1 = fzero, acc2 = fzero;   // m0 x {n0,n1,n2}
  f32x4 acc3 = fzero, acc4 = fzero, acc5 = fzero;   // m1 x {n0,n1,n2}

  uint4 A0, A1, A2, A3, A4, A5, A6, A7;             // x frags buf A (raw fp32 bits)
  uint4 B0, B1, B2, B3, B4, B5, B6, B7;             // buf B
  bf16x8 WA0, WA1, WA2, WA3, WA4, WA5;              // W frags buf A
  bf16x8 WB0, WB1, WB2, WB3, WB4, WB5;              // buf B

#define LD_A(s)                                                            \
  {                                                                        \
    const int c = (s) * 64;                                                \
    A0 = *(const uint4*)(x0 + c);      A1 = *(const uint4*)(x0 + c + 4);   \
    A2 = *(const uint4*)(x0 + c + 32); A3 = *(const uint4*)(x0 + c + 36);  \
    A4 = *(const uint4*)(x1 + c);      A5 = *(const uint4*)(x1 + c + 4);   \
    A6 = *(const uint4*)(x1 + c + 32); A7 = *(const uint4*)(x1 + c + 36);  \
    WA0 = *(const bf16x8*)(w0 + c);    WA1 = *(const bf16x8*)(w0 + c + 32);\
    WA2 = *(const bf16x8*)(w1 + c);    WA3 = *(const bf16x8*)(w1 + c + 32);\
    WA4 = *(const bf16x8*)(w2 + c);    WA5 = *(const bf16x8*)(w2 + c + 32);\
  }
#define LD_B(s)                                                            \
  {                                                                        \
    const int c = (s) * 64;                                                \
    B0 = *(const uint4*)(x0 + c);      B1 = *(const uint4*)(x0 + c + 4);   \
    B2 = *(const uint4*)(x0 + c + 32); B3 = *(const uint4*)(x0 + c + 36);  \
    B4 = *(const uint4*)(x1 + c);      B5 = *(const uint4*)(x1 + c + 4);   \
    B6 = *(const uint4*)(x1 + c + 32); B7 = *(const uint4*)(x1 + c + 36);  \
    WB0 = *(const bf16x8*)(w0 + c);    WB1 = *(const bf16x8*)(w0 + c + 32);\
    WB2 = *(const bf16x8*)(w1 + c);    WB3 = *(const bf16x8*)(w1 + c + 32);\
    WB4 = *(const bf16x8*)(w2 + c);    WB5 = *(const bf16x8*)(w2 + c + 32);\
  }
#define CP_A                                                           \
  {                                                                    \
    bf16x8 a00 = cvt8(A0, A1), a01 = cvt8(A2, A3);                     \
    bf16x8 a10 = cvt8(A4, A5), a11 = cvt8(A6, A7);                     \
    acc0 = MFMA_BF16(a00, WA0, acc0, 0, 0, 0);                         \
    acc0 = MFMA_BF16(a01, WA1, acc0, 0, 0, 0);                         \
    acc1 = MFMA_BF16(a00, WA2, acc1, 0, 0, 0);                         \
    acc1 = MFMA_BF16(a01, WA3, acc1, 0, 0, 0);                         \
    acc2 = MFMA_BF16(a00, WA4, acc2, 0, 0, 0);                         \
    acc2 = MFMA_BF16(a01, WA5, acc2, 0, 0, 0);                         \
    acc3 = MFMA_BF16(a10, WA0, acc3, 0, 0, 0);                         \
    acc3 = MFMA_BF16(a11, WA1, acc3, 0, 0, 0);                         \
    acc4 = MFMA_BF16(a10, WA2, acc4, 0, 0, 0);                         \
    acc4 = MFMA_BF16(a11, WA3, acc4, 0, 0, 0);                         \
    acc5 = MFMA_BF16(a10, WA4, acc5, 0, 0, 0);                         \
    acc5 = MFMA_BF16(a11, WA5, acc5, 0, 0, 0);                         \
  }
#define CP_B                                                           \
  {                                                                    \
    bf16x8 a00 = cvt8(B0, B1), a01 = cvt8(B2, B3);                     \
    bf16x8 a10 = cvt8(B4, B5), a11 = cvt8(B6, B7);                     \
    acc0 = MFMA_BF16(a00, WB0, acc0, 0, 0, 0);                         \
    acc0 = MFMA_BF16(a01, WB1, acc0, 0, 0, 0);                         \
    acc1 = MFMA_BF16(a00, WB2, acc1, 0, 0, 0);                         \
    acc1 = MFMA_BF16(a01, WB3, acc1, 0, 0, 0);                         \
    acc2 = MFMA_BF16(a00, WB4, acc2, 0, 0, 0);                         \
    acc2 = MFMA_BF16(a01, WB5, acc2, 0, 0, 0);                         \
    acc3 = MFMA_BF16(a10, WB0, acc3, 0, 0, 0);                         \
    acc3 = MFMA_BF16(a11, WB1, acc3, 0, 0, 0);                         \
    acc4 = MFMA_BF16(a10, WB2, acc4, 0, 0, 0);                         \
    acc4 = MFMA_BF16(a11, WB3, acc4, 0, 0, 0);                         \
    acc5 = MFMA_BF16(a10, WB4, acc5, 0, 0, 0);                         \
    acc5 = MFMA_BF16(a11, WB5, acc5, 0, 0, 0);                         \
  }

  LD_A(0)
#pragma unroll 1
  for (int s = 0; s < 14; s += 2) {
    LD_B(s + 1)
    __builtin_amdgcn_sched_barrier(0);
    CP_A
    LD_A(s + 2)
    __builtin_amdgcn_sched_barrier(0);
    CP_B
  }
  LD_B(15)
  __builtin_amdgcn_sched_barrier(0);
  CP_A   // k-step 14
  CP_B   // k-step 15

#define ST(AC, m, i)                                                        \
  {                                                                         \
    const int nt = nt0 + (i);                                               \
    if (nt < 4) {                                                           \
      _Pragma("unroll")                                                     \
      for (int r = 0; r < 4; ++r)                                           \
        Qb[(size_t)(r0 + (m) * 16 + laneHi * 4 + r) * 64 + nt * 16 + lane16] = f2bf(AC[r]); \
    } else if (nt < 8) {                                                    \
      _Pragma("unroll")                                                     \
      for (int r = 0; r < 4; ++r)                                           \
        Kb[(size_t)(r0 + (m) * 16 + laneHi * 4 + r) * 64 + (nt - 4) * 16 + lane16] = f2bf(AC[r]); \
    } else {                                                                \
      const int d = (nt - 8) * 16 + lane16;                                 \
      uint2 v;                                                              \
      v.x = cvtpk(AC[0], AC[1]);                                            \
      v.y = cvtpk(AC[2], AC[3]);                                            \
      *(uint2*)(Vt + (size_t)d * 16384 + r0 + (m) * 16 + laneHi * 4) = v;   \
    }                                                                       \
  }

  ST(acc0, 0, 0) ST(acc1, 0, 1) ST(acc2, 0, 2)
  ST(acc3, 1, 0) ST(acc4, 1, 1) ST(acc5, 1, 2)
}

// ---------------- Kernel 2: causal flash attention, register-direct K/V.
// Balanced q-tile map; 4 waves split causal KV range; LDS combine; setprio on MFMA.
#define PLD 72

__global__ __launch_bounds__(256) void attn3(const u16* __restrict__ Qb,
                                             const u16* __restrict__ Kb,
                                             const u16* __restrict__ Vt,
                                             float* __restrict__ out) {
  __shared__ __align__(16) u16 shP[4][16 * PLD];   // per-wave P scratch
  __shared__ float shC[3][64][24];                 // waves 1..3 partials

  const int tid = threadIdx.x, w = tid >> 6, l = tid & 63;
  const int lane16 = l & 15, laneHi = l >> 4;
  const int b = blockIdx.x & 3;
  const int j = blockIdx.x >> 2;
  const int g = j >> 6, r_ = j & 63;
  const int t = (g == 0) ? (255 - r_) : (g == 1) ? r_ : (g == 2) ? (191 - r_) : (64 + r_);
  const int q0 = t * 16, bT = b * 4096;

  const u16* qrow = Qb + (size_t)(bT + q0 + lane16) * 64;
  const bf16x8 qf0 = *(const bf16x8*)(qrow + 8 * laneHi);
  const bf16x8 qf1 = *(const bf16x8*)(qrow + 32 + 8 * laneHi);

  const int n64 = (t + 4) >> 2;                    // ceil((t+1)/4) 64-key units
  const int s = (n64 * w) >> 2, e = (n64 * (w + 1)) >> 2;

  const f32x4 fzero = {0.f, 0.f, 0.f, 0.f};
  f32x4 o[4] = {fzero, fzero, fzero, fzero};
  float mrow[4] = {-INFINITY, -INFINITY, -INFINITY, -INFINITY};
  float lrow[4] = {0.f, 0.f, 0.f, 0.f};

  bf16x8 kA[8], vA[8], kB[8], vB[8];

  auto loadKV = [&](bf16x8 (&kf)[8], bf16x8 (&vf)[8], int u) {
    const int k0 = bT + u * 64;
#pragma unroll
    for (int i = 0; i < 4; ++i) {
      const u16* kp = Kb + (size_t)(k0 + i * 16 + lane16) * 64 + 8 * laneHi;
      kf[i * 2 + 0] = *(const bf16x8*)(kp);
      kf[i * 2 + 1] = *(const bf16x8*)(kp + 32);
      const u16* vp = Vt + (size_t)(i * 16 + lane16) * 16384 + k0 + 8 * laneHi;
      vf[i * 2 + 0] = *(const bf16x8*)(vp);
      vf[i * 2 + 1] = *(const bf16x8*)(vp + 32);
    }
  };

  auto compute = [&](bf16x8 (&kf)[8], bf16x8 (&vf)[8], int u) {
    f32x4 sc[4];
    __builtin_amdgcn_s_setprio(1);
#pragma unroll
    for (int ct = 0; ct < 4; ++ct) {
      f32x4 a = fzero;
      a = MFMA_BF16(qf0, kf[ct * 2 + 0], a, 0, 0, 0);
      a = MFMA_BF16(qf1, kf[ct * 2 + 1], a, 0, 0, 0);
      sc[ct] = a;
    }
    __builtin_amdgcn_s_setprio(0);
    if (u == n64 - 1) {                            // diagonal unit: causal mask
#pragma unroll
      for (int ct = 0; ct < 4; ++ct)
#pragma unroll
        for (int r = 0; r < 4; ++r) {
          const int col = u * 64 + ct * 16 + lane16;
          const int row = q0 + laneHi * 4 + r;
          if (col > row) sc[ct][r] = -INFINITY;
        }
    }
    float mt[4] = {-INFINITY, -INFINITY, -INFINITY, -INFINITY};
#pragma unroll
    for (int ct = 0; ct < 4; ++ct)
#pragma unroll
      for (int r = 0; r < 4; ++r) mt[r] = fmaxf(mt[r], sc[ct][r]);
#pragma unroll
    for (int d = 1; d < 16; d <<= 1)
#pragma unroll
      for (int r = 0; r < 4; ++r) mt[r] = fmaxf(mt[r], __shfl_xor(mt[r], d));

    float alpha[4], rs[4];
#pragma unroll
    for (int r = 0; r < 4; ++r) {
      const float mn = fmaxf(mrow[r], mt[r]);
      alpha[r] = exp2f(mrow[r] - mn);              // base-2 throughout
      mrow[r] = mn;
      rs[r] = 0.f;
    }
#pragma unroll
    for (int ct = 0; ct < 4; ++ct)
#pragma unroll
      for (int r = 0; r < 4; ++r) {
        const float pv = exp2f(sc[ct][r] - mrow[r]);
        rs[r] += pv;
        shP[w][(laneHi * 4 + r) * PLD + ct * 16 + lane16] = f2bf(pv);
      }
#pragma unroll
    for (int d = 1; d < 16; d <<= 1)
#pragma unroll
      for (int r = 0; r < 4; ++r) rs[r] += __shfl_xor(rs[r], d);
#pragma unroll
    for (int r = 0; r < 4; ++r) lrow[r] = lrow[r] * alpha[r] + rs[r];
#pragma unroll
    for (int nt = 0; nt < 4; ++nt)
#pragma unroll
      for (int r = 0; r < 4; ++r) o[nt][r] *= alpha[r];

    asm volatile("s_waitcnt lgkmcnt(0)" ::: "memory");  // wave-local P round-trip

    __builtin_amdgcn_s_setprio(1);
#pragma unroll
    for (int kk = 0; kk < 2; ++kk) {
      bf16x8 pa = *(const bf16x8*)&shP[w][lane16 * PLD + kk * 32 + 8 * laneHi];
#pragma unroll
      for (int nt = 0; nt < 4; ++nt)
        o[nt] = MFMA_BF16(pa, vf[nt * 2 + kk], o[nt], 0, 0, 0);
    }
    __builtin_amdgcn_s_setprio(0);
  };

  // main loop: 2x unrolled with double-buffered K/V fragment registers
  int u = s;
  if (u < e) loadKV(kA, vA, u);
  while (u < e) {
    if (u + 1 < e) loadKV(kB, vB, u + 1);
    compute(kA, vA, u);
    ++u;
    if (u >= e) break;
    if (u + 1 < e) loadKV(kA, vA, u + 1);
    compute(kB, vB, u);
    ++u;
  }

  // combine: waves 1..3 publish partials, wave 0 merges + writes out
  if (w > 0) {
    float* dst = &shC[w - 1][l][0];
#pragma unroll
    for (int r = 0; r < 4; ++r) { dst[r] = mrow[r]; dst[4 + r] = lrow[r]; }
#pragma unroll
    for (int nt = 0; nt < 4; ++nt)
#pragma unroll
      for (int r = 0; r < 4; ++r) dst[8 + nt * 4 + r] = o[nt][r];
  }
  __syncthreads();
  if (w == 0) {
#pragma unroll
    for (int peer = 0; peer < 3; ++peer) {
      const float* src = &shC[peer][l][0];
#pragma unroll
      for (int r = 0; r < 4; ++r) {
        const float pm = src[r], pl = src[4 + r];
        const float mn = fmaxf(mrow[r], pm);
        // fmaxf(NaN, -80) -> -80 : branchless guard for empty partials
        const float aS = exp2f(fmaxf(mrow[r] - mn, -80.f));
        const float aP = exp2f(fmaxf(pm - mn, -80.f));
        mrow[r] = mn;
        lrow[r] = lrow[r] * aS + pl * aP;
#pragma unroll
        for (int nt = 0; nt < 4; ++nt)
          o[nt][r] = o[nt][r] * aS + src[8 + nt * 4 + r] * aP;
      }
    }
    float inv[4];
#pragma unroll
    for (int r = 0; r < 4; ++r) inv[r] = 1.0f / lrow[r];
#pragma unroll
    for (int nt = 0; nt < 4; ++nt)
#pragma unroll
      for (int r = 0; r < 4; ++r)
        out[(size_t)(bT + q0 + laneHi * 4 + r) * 64 + nt * 16 + lane16] = o[nt][r] * inv[r];
  }
}

extern "C" void kernel_launch(void* const* d_in, const int* in_sizes, int n_in,
                              void* d_out, int out_size, void* d_ws, size_t ws_size,
                              hipStream_t stream) {
  const float* x  = (const float*)d_in[0];
  const float* Wq = (const float*)d_in[1];
  const float* Wk = (const float*)d_in[2];
  const float* Wv = (const float*)d_in[3];
  float* out = (float*)d_out;

  char* ws = (char*)d_ws;
  u16* Wt = (u16*)ws;                                   // 192*1024*2   = 384 KiB
  u16* Qb = (u16*)(ws + 393216);                        // 16384*64*2   = 2 MiB
  u16* Kb = (u16*)(ws + 393216 + 2097152);
  u16* Vt = (u16*)(ws + 393216 + 2 * 2097152);          // transposed V [64][16384]

  wt_kernel<<<192, 256, 0, stream>>>(Wq, Wk, Wv, Wt);
  qkv5<<<512, 256, 0, stream>>>(x, Wt, Qb, Kb, Vt);
  attn3<<<1024, 256, 0, stream>>>(Qb, Kb, Vt, out);
}

// Round 9
// 98.471 us; speedup vs baseline: 1.5411x; 1.3401x over previous
//
#include <hip/hip_runtime.h>

typedef short bf16x8 __attribute__((ext_vector_type(8)));
typedef float f32x4 __attribute__((ext_vector_type(4)));
typedef float f32x16 __attribute__((ext_vector_type(16)));
typedef unsigned short u16;
typedef unsigned int u32;

#define MFMA_BF16 __builtin_amdgcn_mfma_f32_16x16x32_bf16
#define MFMA32 __builtin_amdgcn_mfma_f32_32x32x16_bf16

static __device__ __forceinline__ u16 f2bf(float f) {
  union { float f; unsigned u; } v; v.f = f;
  return (u16)((v.u + 0x7FFFu + ((v.u >> 16) & 1u)) >> 16);  // RNE
}
static __device__ __forceinline__ u32 cvtpk(float lo, float hi) {
  u32 r;
  asm("v_cvt_pk_bf16_f32 %0, %1, %2" : "=v"(r) : "v"(lo), "v"(hi));
  return r;  // lo -> bits[15:0], hi -> bits[31:16]
}
static __device__ __forceinline__ bf16x8 cvt8(uint4 p, uint4 q) {  // 8 fp32 (raw bits) -> bf16x8
  union { u32 w[4]; bf16x8 b; } r;
  r.w[0] = cvtpk(__uint_as_float(p.x), __uint_as_float(p.y));
  r.w[1] = cvtpk(__uint_as_float(p.z), __uint_as_float(p.w));
  r.w[2] = cvtpk(__uint_as_float(q.x), __uint_as_float(q.y));
  r.w[3] = cvtpk(__uint_as_float(q.z), __uint_as_float(q.w));
  return r.b;
}
static __device__ __forceinline__ float xhalf(float x) { return __shfl_xor(x, 32); }
static __device__ __forceinline__ u32 xhalfu(u32 x) { return (u32)__shfl_xor((int)x, 32); }

// ---------------- Kernel 0: W -> Wt[192][1024] bf16; Q gets 1/sqrt(64)*log2(e) folded in
__global__ __launch_bounds__(256) void wt_kernel(const float* __restrict__ Wq,
                                                 const float* __restrict__ Wk,
                                                 const float* __restrict__ Wv,
                                                 u16* __restrict__ Wt) {
  const int nrow = blockIdx.x;               // 0..191
  const int m = nrow >> 6, n = nrow & 63;
  const float* W = (m == 0) ? Wq : ((m == 1) ? Wk : Wv);
  const float s = (m == 0) ? 0.125f * 1.44269504f : 1.0f;  // scores in base-2 units
  for (int k = threadIdx.x; k < 1024; k += 256)
    Wt[(size_t)nrow * 1024 + k] = f2bf(W[(size_t)k * 64 + n] * s);
}

// ---------------- Kernel 1: QKV projection, pipelined register-direct GEMM (unchanged).
__global__ __launch_bounds__(256) void qkv5(const float* __restrict__ x,
                                            const u16* __restrict__ Wt,
                                            u16* __restrict__ Qb,
                                            u16* __restrict__ Kb,
                                            u16* __restrict__ Vt) {
  const int w = threadIdx.x >> 6, l = threadIdx.x & 63;
  const int lane16 = l & 15, laneHi = l >> 4;
  const int r0 = blockIdx.x * 32;
  const int nt0 = w * 3;
  const float* x0 = x + (size_t)(r0 + lane16) * 1024 + 8 * laneHi;      // M-frag 0
  const float* x1 = x0 + 16 * 1024;                                     // M-frag 1
  const u16* w0 = Wt + (size_t)((nt0 + 0) * 16 + lane16) * 1024 + 8 * laneHi;
  const u16* w1 = Wt + (size_t)((nt0 + 1) * 16 + lane16) * 1024 + 8 * laneHi;
  const u16* w2 = Wt + (size_t)((nt0 + 2) * 16 + lane16) * 1024 + 8 * laneHi;

  const f32x4 fzero = {0.f, 0.f, 0.f, 0.f};
  f32x4 acc0 = fzero, acc1 = fzero, acc2 = fzero;   // m0 x {n0,n1,n2}
  f32x4 acc3 = fzero, acc4 = fzero, acc5 = fzero;   // m1 x {n0,n1,n2}

  uint4 A0, A1, A2, A3, A4, A5, A6, A7;             // x frags buf A (raw fp32 bits)
  uint4 B0, B1, B2, B3, B4, B5, B6, B7;             // buf B
  bf16x8 WA0, WA1, WA2, WA3, WA4, WA5;              // W frags buf A
  bf16x8 WB0, WB1, WB2, WB3, WB4, WB5;              // buf B

#define LD_A(s)                                                            \
  {                                                                        \
    const int c = (s) * 64;                                                \
    A0 = *(const uint4*)(x0 + c);      A1 = *(const uint4*)(x0 + c + 4);   \
    A2 = *(const uint4*)(x0 + c + 32); A3 = *(const uint4*)(x0 + c + 36);  \
    A4 = *(const uint4*)(x1 + c);      A5 = *(const uint4*)(x1 + c + 4);   \
    A6 = *(const uint4*)(x1 + c + 32); A7 = *(const uint4*)(x1 + c + 36);  \
    WA0 = *(const bf16x8*)(w0 + c);    WA1 = *(const bf16x8*)(w0 + c + 32);\
    WA2 = *(const bf16x8*)(w1 + c);    WA3 = *(const bf16x8*)(w1 + c + 32);\
    WA4 = *(const bf16x8*)(w2 + c);    WA5 = *(const bf16x8*)(w2 + c + 32);\
  }
#define LD_B(s)                                                            \
  {                                                                        \
    const int c = (s) * 64;                                                \
    B0 = *(const uint4*)(x0 + c);      B1 = *(const uint4*)(x0 + c + 4);   \
    B2 = *(const uint4*)(x0 + c + 32); B3 = *(const uint4*)(x0 + c + 36);  \
    B4 = *(const uint4*)(x1 + c);      B5 = *(const uint4*)(x1 + c + 4);   \
    B6 = *(const uint4*)(x1 + c + 32); B7 = *(const uint4*)(x1 + c + 36);  \
    WB0 = *(const bf16x8*)(w0 + c);    WB1 = *(const bf16x8*)(w0 + c + 32);\
    WB2 = *(const bf16x8*)(w1 + c);    WB3 = *(const bf16x8*)(w1 + c + 32);\
    WB4 = *(const bf16x8*)(w2 + c);    WB5 = *(const bf16x8*)(w2 + c + 32);\
  }
#define CP_A                                                           \
  {                                                                    \
    bf16x8 a00 = cvt8(A0, A1), a01 = cvt8(A2, A3);                     \
    bf16x8 a10 = cvt8(A4, A5), a11 = cvt8(A6, A7);                     \
    acc0 = MFMA_BF16(a00, WA0, acc0, 0, 0, 0);                         \
    acc0 = MFMA_BF16(a01, WA1, acc0, 0, 0, 0);                         \
    acc1 = MFMA_BF16(a00, WA2, acc1, 0, 0, 0);                         \
    acc1 = MFMA_BF16(a01, WA3, acc1, 0, 0, 0);                         \
    acc2 = MFMA_BF16(a00, WA4, acc2, 0, 0, 0);                         \
    acc2 = MFMA_BF16(a01, WA5, acc2, 0, 0, 0);                         \
    acc3 = MFMA_BF16(a10, WA0, acc3, 0, 0, 0);                         \
    acc3 = MFMA_BF16(a11, WA1, acc3, 0, 0, 0);                         \
    acc4 = MFMA_BF16(a10, WA2, acc4, 0, 0, 0);                         \
    acc4 = MFMA_BF16(a11, WA3, acc4, 0, 0, 0);                         \
    acc5 = MFMA_BF16(a10, WA4, acc5, 0, 0, 0);                         \
    acc5 = MFMA_BF16(a11, WA5, acc5, 0, 0, 0);                         \
  }
#define CP_B                                                           \
  {                                                                    \
    bf16x8 a00 = cvt8(B0, B1), a01 = cvt8(B2, B3);                     \
    bf16x8 a10 = cvt8(B4, B5), a11 = cvt8(B6, B7);                     \
    acc0 = MFMA_BF16(a00, WB0, acc0, 0, 0, 0);                         \
    acc0 = MFMA_BF16(a01, WB1, acc0, 0, 0, 0);                         \
    acc1 = MFMA_BF16(a00, WB2, acc1, 0, 0, 0);                         \
    acc1 = MFMA_BF16(a01, WB3, acc1, 0, 0, 0);                         \
    acc2 = MFMA_BF16(a00, WB4, acc2, 0, 0, 0);                         \
    acc2 = MFMA_BF16(a01, WB5, acc2, 0, 0, 0);                         \
    acc3 = MFMA_BF16(a10, WB0, acc3, 0, 0, 0);                         \
    acc3 = MFMA_BF16(a11, WB1, acc3, 0, 0, 0);                         \
    acc4 = MFMA_BF16(a10, WB2, acc4, 0, 0, 0);                         \
    acc4 = MFMA_BF16(a11, WB3, acc4, 0, 0, 0);                         \
    acc5 = MFMA_BF16(a10, WB4, acc5, 0, 0, 0);                         \
    acc5 = MFMA_BF16(a11, WB5, acc5, 0, 0, 0);                         \
  }

  LD_A(0)
#pragma unroll 1
  for (int s = 0; s < 14; s += 2) {
    LD_B(s + 1)
    __builtin_amdgcn_sched_barrier(0);
    CP_A
    LD_A(s + 2)
    __builtin_amdgcn_sched_barrier(0);
    CP_B
  }
  LD_B(15)
  __builtin_amdgcn_sched_barrier(0);
  CP_A
  CP_B

#define ST(AC, m, i)                                                        \
  {                                                                         \
    const int nt = nt0 + (i);                                               \
    if (nt < 4) {                                                           \
      _Pragma("unroll")                                                     \
      for (int r = 0; r < 4; ++r)                                           \
        Qb[(size_t)(r0 + (m) * 16 + laneHi * 4 + r) * 64 + nt * 16 + lane16] = f2bf(AC[r]); \
    } else if (nt < 8) {                                                    \
      _Pragma("unroll")                                                     \
      for (int r = 0; r < 4; ++r)                                           \
        Kb[(size_t)(r0 + (m) * 16 + laneHi * 4 + r) * 64 + (nt - 4) * 16 + lane16] = f2bf(AC[r]); \
    } else {                                                                \
      const int d = (nt - 8) * 16 + lane16;                                 \
      uint2 v;                                                              \
      v.x = cvtpk(AC[0], AC[1]);                                            \
      v.y = cvtpk(AC[2], AC[3]);                                            \
      *(uint2*)(Vt + (size_t)d * 16384 + r0 + (m) * 16 + laneHi * 4) = v;   \
    }                                                                       \
  }

  ST(acc0, 0, 0) ST(acc1, 0, 1) ST(acc2, 0, 2)
  ST(acc3, 1, 0) ST(acc4, 1, 1) ST(acc5, 1, 2)
}

// ---------------- Kernel 2: swapped-QK^T 32x32 flash attention (shfl-based cross-half).
// Grid 512 = 4 batches x 128 q-tiles (32 rows); t-pairing balances CUs.
// S^T = mfma(K, Q): lane owns col=q; key=(r&3)+8*(r>>2)+4*hi. Softmax in-register;
// cross-half exchanges via __shfl_xor(.,32). P -> PV B-frag: cvtpk + shfl + select.
// O^T = mfma(V^T, P): col=q -> rescale lane-local. 4 waves split KV; LDS combine.
__global__ __launch_bounds__(256) void attn4(const u16* __restrict__ Qb,
                                             const u16* __restrict__ Kb,
                                             const u16* __restrict__ Vt,
                                             float* __restrict__ out) {
  __shared__ float shC[3][64][37];                 // waves 1..3 partials
  __shared__ __align__(16) float shT[32][68];      // output transpose staging

  const int tid = threadIdx.x, w = tid >> 6, l = tid & 63;
  const int q = l & 31, hi = l >> 5;
  const bool isHi = hi != 0;
  const int b = blockIdx.x & 3;
  const int j = blockIdx.x >> 2;                   // 0..127
  const int t = (j >> 6) ? (j & 63) : (127 - (j & 63));
  const int q0 = t * 32, bT = b * 4096;

  // Q fragments (B-operand: col=q, k=d), resident
  const u16* qp = Qb + (size_t)(bT + q0 + q) * 64 + 8 * hi;
  const bf16x8 qf0 = *(const bf16x8*)(qp);
  const bf16x8 qf1 = *(const bf16x8*)(qp + 16);
  const bf16x8 qf2 = *(const bf16x8*)(qp + 32);
  const bf16x8 qf3 = *(const bf16x8*)(qp + 48);

  const int nu = t + 1;                            // 32-key units in causal range
  const int s = (nu * w) >> 2, e = (nu * (w + 1)) >> 2;

  f32x16 o0 = {}, o1 = {};                         // O^T: col=q, rows=d (2 d-tiles)
  float m = -INFINITY, lsum = 0.f;

  bf16x8 kA[4], vA[4], kB[4], vB[4];

  auto loadKV = [&](bf16x8 (&kf)[4], bf16x8 (&vf)[4], int u) {
    const int k0 = bT + u * 32;
    const u16* kp = Kb + (size_t)(k0 + q) * 64 + 8 * hi;
#pragma unroll
    for (int kc = 0; kc < 4; ++kc) kf[kc] = *(const bf16x8*)(kp + kc * 16);
#pragma unroll
    for (int dt = 0; dt < 2; ++dt)
#pragma unroll
      for (int c = 0; c < 2; ++c)
        vf[dt * 2 + c] = *(const bf16x8*)(Vt + (size_t)(dt * 32 + q) * 16384 + k0 + c * 16 + 8 * hi);
  };

  auto compute = [&](bf16x8 (&kf)[4], bf16x8 (&vf)[4], int u) {
    // ---- S^T = K Q (rows=keys, cols=q)
    f32x16 sc = {};
    __builtin_amdgcn_s_setprio(1);
    sc = MFMA32(kf[0], qf0, sc, 0, 0, 0);
    sc = MFMA32(kf[1], qf1, sc, 0, 0, 0);
    sc = MFMA32(kf[2], qf2, sc, 0, 0, 0);
    sc = MFMA32(kf[3], qf3, sc, 0, 0, 0);
    __builtin_amdgcn_s_setprio(0);

    if (u == t) {                                  // diagonal unit: causal mask
#pragma unroll
      for (int r = 0; r < 16; ++r) {
        const int key = (r & 3) + 8 * (r >> 2) + 4 * hi;
        if (key > q) sc[r] = -INFINITY;
      }
    }

    // ---- row max: lane-local 16 + one cross-half shfl
    float pm = sc[0];
#pragma unroll
    for (int r = 1; r < 16; ++r) pm = fmaxf(pm, sc[r]);
    pm = fmaxf(pm, xhalf(pm));

    // ---- defer-max rescale (T13, THR=8 in base-2 units); guarded exp2
    if (!__all(pm <= m + 8.f)) {
      const float mn = fmaxf(m, pm);
      const float al = exp2f(fmaxf(m - mn, -80.f));   // guard -inf - -inf
#pragma unroll
      for (int r = 0; r < 16; ++r) { o0[r] *= al; o1[r] *= al; }
      lsum *= al;
      m = mn;
    }

    // ---- P = exp2(S - m), row sum
    float p[16];
    float rs = 0.f;
#pragma unroll
    for (int r = 0; r < 16; ++r) { p[r] = exp2f(sc[r] - m); rs += p[r]; }
    rs += xhalf(rs);
    lsum += rs;

    // ---- P -> PV B-frags (contiguous-8 k-mapping): cvtpk + shfl + half-select
    u32 wl0 = cvtpk(p[0], p[1]),  wl1 = cvtpk(p[2], p[3]);
    u32 wh0 = cvtpk(p[4], p[5]),  wh1 = cvtpk(p[6], p[7]);
    u32 yl0 = cvtpk(p[8], p[9]),  yl1 = cvtpk(p[10], p[11]);
    u32 yh0 = cvtpk(p[12], p[13]), yh1 = cvtpk(p[14], p[15]);
    u32 sl0 = xhalfu(wl0), sl1 = xhalfu(wl1);
    u32 sh0 = xhalfu(wh0), sh1 = xhalfu(wh1);
    u32 tl0 = xhalfu(yl0), tl1 = xhalfu(yl1);
    u32 th0 = xhalfu(yh0), th1 = xhalfu(yh1);
    union { u32 w4[4]; bf16x8 v; } pf0, pf1;
    pf0.w4[0] = isHi ? sh0 : wl0;   // j0,1: keys 8h+0,1
    pf0.w4[1] = isHi ? sh1 : wl1;   // j2,3: keys 8h+2,3
    pf0.w4[2] = isHi ? wh0 : sl0;   // j4,5: keys 8h+4,5
    pf0.w4[3] = isHi ? wh1 : sl1;   // j6,7: keys 8h+6,7
    pf1.w4[0] = isHi ? th0 : yl0;   // keys 16+8h+0,1
    pf1.w4[1] = isHi ? th1 : yl1;
    pf1.w4[2] = isHi ? yh0 : tl0;
    pf1.w4[3] = isHi ? yh1 : tl1;

    // ---- O^T += V^T P (rows=d, cols=q)
    __builtin_amdgcn_s_setprio(1);
    o0 = MFMA32(vf[0], pf0.v, o0, 0, 0, 0);
    o0 = MFMA32(vf[1], pf1.v, o0, 0, 0, 0);
    o1 = MFMA32(vf[2], pf0.v, o1, 0, 0, 0);
    o1 = MFMA32(vf[3], pf1.v, o1, 0, 0, 0);
    __builtin_amdgcn_s_setprio(0);
  };

  // main loop: 2x unrolled, double-buffered K/V fragments
  int u = s;
  if (u < e) loadKV(kA, vA, u);
  while (u < e) {
    if (u + 1 < e) loadKV(kB, vB, u + 1);
    compute(kA, vA, u);
    ++u;
    if (u >= e) break;
    if (u + 1 < e) loadKV(kA, vA, u + 1);
    compute(kB, vB, u);
    ++u;
  }

  // ---- combine: waves 1..3 publish, wave 0 merges
  if (w > 0) {
    float* dst = &shC[w - 1][l][0];
    dst[0] = m; dst[1] = lsum;
#pragma unroll
    for (int r = 0; r < 16; ++r) { dst[2 + r] = o0[r]; dst[18 + r] = o1[r]; }
  }
  __syncthreads();
  if (w == 0) {
#pragma unroll
    for (int peer = 0; peer < 3; ++peer) {
      const float* src = &shC[peer][l][0];
      const float pm = src[0], pl = src[1];
      const float mn = fmaxf(m, pm);
      const float aS = exp2f(fmaxf(m - mn, -80.f));   // NaN(-inf - -inf) -> -80 guard
      const float aP = exp2f(fmaxf(pm - mn, -80.f));
      m = mn;
      lsum = lsum * aS + pl * aP;
#pragma unroll
      for (int r = 0; r < 16; ++r) {
        o0[r] = o0[r] * aS + src[2 + r] * aP;
        o1[r] = o1[r] * aS + src[18 + r] * aP;
      }
    }
    const float inv = 1.0f / lsum;
    // stage O (rows=q, cols=d) into LDS for coalesced output
#pragma unroll
    for (int r = 0; r < 16; ++r) {
      const int d = (r & 3) + 8 * (r >> 2) + 4 * hi;
      shT[q][d] = o0[r] * inv;
      shT[q][32 + d] = o1[r] * inv;
    }
    __asm volatile("s_waitcnt lgkmcnt(0)" ::: "memory");  // same-wave LDS RAW
#pragma unroll
    for (int it = 0; it < 8; ++it) {
      const int row = it * 4 + (l >> 4);
      const int c4 = (l & 15) * 4;
      float4 v = *(const float4*)&shT[row][c4];
      *(float4*)(out + (size_t)(bT + q0 + row) * 64 + c4) = v;
    }
  }
}

extern "C" void kernel_launch(void* const* d_in, const int* in_sizes, int n_in,
                              void* d_out, int out_size, void* d_ws, size_t ws_size,
                              hipStream_t stream) {
  const float* x  = (const float*)d_in[0];
  const float* Wq = (const float*)d_in[1];
  const float* Wk = (const float*)d_in[2];
  const float* Wv = (const float*)d_in[3];
  float* out = (float*)d_out;

  char* ws = (char*)d_ws;
  u16* Wt = (u16*)ws;                                   // 192*1024*2   = 384 KiB
  u16* Qb = (u16*)(ws + 393216);                        // 16384*64*2   = 2 MiB
  u16* Kb = (u16*)(ws + 393216 + 2097152);
  u16* Vt = (u16*)(ws + 393216 + 2 * 2097152);          // transposed V [64][16384]

  wt_kernel<<<192, 256, 0, stream>>>(Wq, Wk, Wv, Wt);
  qkv5<<<512, 256, 0, stream>>>(x, Wt, Qb, Kb, Vt);
  attn4<<<512, 256, 0, stream>>>(Qb, Kb, Vt, out);
}

// Round 10
// 78.363 us; speedup vs baseline: 1.9366x; 1.2566x over previous
//
#include <hip/hip_runtime.h>

typedef short bf16x8 __attribute__((ext_vector_type(8)));
typedef float f32x4 __attribute__((ext_vector_type(4)));
typedef float f32x16 __attribute__((ext_vector_type(16)));
typedef unsigned short u16;
typedef unsigned int u32;

#define MFMA_BF16 __builtin_amdgcn_mfma_f32_16x16x32_bf16
#define MFMA32 __builtin_amdgcn_mfma_f32_32x32x16_bf16

static __device__ __forceinline__ u16 f2bf(float f) {
  union { float f; unsigned u; } v; v.f = f;
  return (u16)((v.u + 0x7FFFu + ((v.u >> 16) & 1u)) >> 16);  // RNE
}
static __device__ __forceinline__ u32 cvtpk(float lo, float hi) {
  u32 r;
  asm("v_cvt_pk_bf16_f32 %0, %1, %2" : "=v"(r) : "v"(lo), "v"(hi));
  return r;  // lo -> bits[15:0], hi -> bits[31:16]
}
static __device__ __forceinline__ bf16x8 cvt8(uint4 p, uint4 q) {  // 8 fp32 (raw bits) -> bf16x8
  union { u32 w[4]; bf16x8 b; } r;
  r.w[0] = cvtpk(__uint_as_float(p.x), __uint_as_float(p.y));
  r.w[1] = cvtpk(__uint_as_float(p.z), __uint_as_float(p.w));
  r.w[2] = cvtpk(__uint_as_float(q.x), __uint_as_float(q.y));
  r.w[3] = cvtpk(__uint_as_float(q.z), __uint_as_float(q.w));
  return r.b;
}
static __device__ __forceinline__ float xhalf(float x) { return __shfl_xor(x, 32); }
static __device__ __forceinline__ u32 xhalfu(u32 x) { return (u32)__shfl_xor((int)x, 32); }

// async global -> LDS, 16B per lane; LDS dest = wave-uniform base + lane*16
static __device__ __forceinline__ void gload16(const void* g, void* l) {
  __builtin_amdgcn_global_load_lds(
      (const __attribute__((address_space(1))) u32*)g,
      (__attribute__((address_space(3))) u32*)l, 16, 0, 0);
}

// ---------------- Kernel 0: W -> Wt[192][1024] bf16; Q gets 1/sqrt(64)*log2(e) folded in
__global__ __launch_bounds__(256) void wt_kernel(const float* __restrict__ Wq,
                                                 const float* __restrict__ Wk,
                                                 const float* __restrict__ Wv,
                                                 u16* __restrict__ Wt) {
  const int nrow = blockIdx.x;               // 0..191
  const int m = nrow >> 6, n = nrow & 63;
  const float* W = (m == 0) ? Wq : ((m == 1) ? Wk : Wv);
  const float s = (m == 0) ? 0.125f * 1.44269504f : 1.0f;  // scores in base-2 units
  for (int k = threadIdx.x; k < 1024; k += 256)
    Wt[(size_t)nrow * 1024 + k] = f2bf(W[(size_t)k * 64 + n] * s);
}

// ---------------- Kernel 1: QKV projection via global_load_lds (m97 structure).
// 512 blocks x 32 rows, BN=192 (x read once), BK=64, double-buffered 64KB LDS.
// LDS is FRAGMENT-MAJOR: 32 slots of 1KB per buffer; slot written by one
// global_load_lds_dwordx4 (lane-linear) and read back lane-linear -> no conflicts.
// slots 0..23: W (nt=slot/2, kh=slot%2). slots 24..31: x (m,kh,p), fp32 pieces.
// Waves 0-2 stage W (8 slots each), wave 3 stages x (8 slots).
__global__ __launch_bounds__(256) void qkv6(const float* __restrict__ x,
                                            const u16* __restrict__ Wt,
                                            u16* __restrict__ Qb,
                                            u16* __restrict__ Kb,
                                            u16* __restrict__ Vt) {
  __shared__ __align__(16) char sh[2][32 * 1024];
  const int w = threadIdx.x >> 6, l = threadIdx.x & 63;
  const int lane16 = l & 15, laneHi = l >> 4;
  const int r0 = blockIdx.x * 32;
  const int nt0 = w * 3;

  const f32x4 fzero = {0.f, 0.f, 0.f, 0.f};
  f32x4 acc0 = fzero, acc1 = fzero, acc2 = fzero;   // m0 x {nt0,nt0+1,nt0+2}
  f32x4 acc3 = fzero, acc4 = fzero, acc5 = fzero;   // m1 x {nt0,nt0+1,nt0+2}

  auto stage = [&](int buf, int s) {
    char* base = &sh[buf][0];
    const int k0 = s * 64;
    if (w < 3) {
#pragma unroll
      for (int ii = 0; ii < 8; ++ii) {
        const int nt = w * 4 + (ii >> 1), kh = ii & 1;
        const u16* g = Wt + (size_t)(nt * 16 + lane16) * 1024 + k0 + kh * 32 + laneHi * 8;
        gload16(g, base + (nt * 2 + kh) * 1024);
      }
    } else {
#pragma unroll
      for (int ii = 0; ii < 8; ++ii) {
        const int m = ii >> 2, kh = (ii >> 1) & 1, p = ii & 1;
        const float* g = x + (size_t)(r0 + m * 16 + lane16) * 1024 + k0 + kh * 32 + laneHi * 8 + p * 4;
        gload16(g, base + (24 + ii) * 1024);
      }
    }
  };

  auto comp = [&](int buf) {
    const char* base = &sh[buf][0] + (size_t)l * 16;
    bf16x8 b00 = *(const bf16x8*)(base + ((nt0 + 0) * 2 + 0) * 1024);
    bf16x8 b01 = *(const bf16x8*)(base + ((nt0 + 0) * 2 + 1) * 1024);
    bf16x8 b10 = *(const bf16x8*)(base + ((nt0 + 1) * 2 + 0) * 1024);
    bf16x8 b11 = *(const bf16x8*)(base + ((nt0 + 1) * 2 + 1) * 1024);
    bf16x8 b20 = *(const bf16x8*)(base + ((nt0 + 2) * 2 + 0) * 1024);
    bf16x8 b21 = *(const bf16x8*)(base + ((nt0 + 2) * 2 + 1) * 1024);
    uint4 x00a = *(const uint4*)(base + 24 * 1024);
    uint4 x00b = *(const uint4*)(base + 25 * 1024);
    uint4 x01a = *(const uint4*)(base + 26 * 1024);
    uint4 x01b = *(const uint4*)(base + 27 * 1024);
    uint4 x10a = *(const uint4*)(base + 28 * 1024);
    uint4 x10b = *(const uint4*)(base + 29 * 1024);
    uint4 x11a = *(const uint4*)(base + 30 * 1024);
    uint4 x11b = *(const uint4*)(base + 31 * 1024);
    bf16x8 a00 = cvt8(x00a, x00b);   // m0, k 0-31 slice
    bf16x8 a01 = cvt8(x01a, x01b);   // m0, k 32-63
    bf16x8 a10 = cvt8(x10a, x10b);   // m1, k 0-31
    bf16x8 a11 = cvt8(x11a, x11b);   // m1, k 32-63
    acc0 = MFMA_BF16(a00, b00, acc0, 0, 0, 0);
    acc0 = MFMA_BF16(a01, b01, acc0, 0, 0, 0);
    acc1 = MFMA_BF16(a00, b10, acc1, 0, 0, 0);
    acc1 = MFMA_BF16(a01, b11, acc1, 0, 0, 0);
    acc2 = MFMA_BF16(a00, b20, acc2, 0, 0, 0);
    acc2 = MFMA_BF16(a01, b21, acc2, 0, 0, 0);
    acc3 = MFMA_BF16(a10, b00, acc3, 0, 0, 0);
    acc3 = MFMA_BF16(a11, b01, acc3, 0, 0, 0);
    acc4 = MFMA_BF16(a10, b10, acc4, 0, 0, 0);
    acc4 = MFMA_BF16(a11, b11, acc4, 0, 0, 0);
    acc5 = MFMA_BF16(a10, b20, acc5, 0, 0, 0);
    acc5 = MFMA_BF16(a11, b21, acc5, 0, 0, 0);
  };

  stage(0, 0);
  __syncthreads();
#pragma unroll 1
  for (int s = 0; s < 16; ++s) {
    if (s + 1 < 16) stage((s + 1) & 1, s + 1);   // async prefetch, no VGPR cost
    comp(s & 1);
    __syncthreads();                              // drains vmcnt; buf swap safe
  }

#define ST(AC, m, i)                                                        \
  {                                                                         \
    const int nt = nt0 + (i);                                               \
    if (nt < 4) {                                                           \
      _Pragma("unroll")                                                     \
      for (int r = 0; r < 4; ++r)                                           \
        Qb[(size_t)(r0 + (m) * 16 + laneHi * 4 + r) * 64 + nt * 16 + lane16] = f2bf(AC[r]); \
    } else if (nt < 8) {                                                    \
      _Pragma("unroll")                                                     \
      for (int r = 0; r < 4; ++r)                                           \
        Kb[(size_t)(r0 + (m) * 16 + laneHi * 4 + r) * 64 + (nt - 4) * 16 + lane16] = f2bf(AC[r]); \
    } else {                                                                \
      const int d = (nt - 8) * 16 + lane16;                                 \
      uint2 v;                                                              \
      v.x = cvtpk(AC[0], AC[1]);                                            \
      v.y = cvtpk(AC[2], AC[3]);                                            \
      *(uint2*)(Vt + (size_t)d * 16384 + r0 + (m) * 16 + laneHi * 4) = v;   \
    }                                                                       \
  }

  ST(acc0, 0, 0) ST(acc1, 0, 1) ST(acc2, 0, 2)
  ST(acc3, 1, 0) ST(acc4, 1, 1) ST(acc5, 1, 2)
}

// ---------------- Kernel 2: swapped-QK^T 32x32 flash attention (unchanged).
__global__ __launch_bounds__(256) void attn4(const u16* __restrict__ Qb,
                                             const u16* __restrict__ Kb,
                                             const u16* __restrict__ Vt,
                                             float* __restrict__ out) {
  __shared__ float shC[3][64][37];                 // waves 1..3 partials
  __shared__ __align__(16) float shT[32][68];      // output transpose staging

  const int tid = threadIdx.x, w = tid >> 6, l = tid & 63;
  const int q = l & 31, hi = l >> 5;
  const bool isHi = hi != 0;
  const int b = blockIdx.x & 3;
  const int j = blockIdx.x >> 2;                   // 0..127
  const int t = (j >> 6) ? (j & 63) : (127 - (j & 63));
  const int q0 = t * 32, bT = b * 4096;

  // Q fragments (B-operand: col=q, k=d), resident
  const u16* qp = Qb + (size_t)(bT + q0 + q) * 64 + 8 * hi;
  const bf16x8 qf0 = *(const bf16x8*)(qp);
  const bf16x8 qf1 = *(const bf16x8*)(qp + 16);
  const bf16x8 qf2 = *(const bf16x8*)(qp + 32);
  const bf16x8 qf3 = *(const bf16x8*)(qp + 48);

  const int nu = t + 1;                            // 32-key units in causal range
  const int s = (nu * w) >> 2, e = (nu * (w + 1)) >> 2;

  f32x16 o0 = {}, o1 = {};                         // O^T: col=q, rows=d (2 d-tiles)
  float m = -INFINITY, lsum = 0.f;

  bf16x8 kA[4], vA[4], kB[4], vB[4];

  auto loadKV = [&](bf16x8 (&kf)[4], bf16x8 (&vf)[4], int u) {
    const int k0 = bT + u * 32;
    const u16* kp = Kb + (size_t)(k0 + q) * 64 + 8 * hi;
#pragma unroll
    for (int kc = 0; kc < 4; ++kc) kf[kc] = *(const bf16x8*)(kp + kc * 16);
#pragma unroll
    for (int dt = 0; dt < 2; ++dt)
#pragma unroll
      for (int c = 0; c < 2; ++c)
        vf[dt * 2 + c] = *(const bf16x8*)(Vt + (size_t)(dt * 32 + q) * 16384 + k0 + c * 16 + 8 * hi);
  };

  auto compute = [&](bf16x8 (&kf)[4], bf16x8 (&vf)[4], int u) {
    // ---- S^T = K Q (rows=keys, cols=q)
    f32x16 sc = {};
    __builtin_amdgcn_s_setprio(1);
    sc = MFMA32(kf[0], qf0, sc, 0, 0, 0);
    sc = MFMA32(kf[1], qf1, sc, 0, 0, 0);
    sc = MFMA32(kf[2], qf2, sc, 0, 0, 0);
    sc = MFMA32(kf[3], qf3, sc, 0, 0, 0);
    __builtin_amdgcn_s_setprio(0);

    if (u == t) {                                  // diagonal unit: causal mask
#pragma unroll
      for (int r = 0; r < 16; ++r) {
        const int key = (r & 3) + 8 * (r >> 2) + 4 * hi;
        if (key > q) sc[r] = -INFINITY;
      }
    }

    // ---- row max: lane-local 16 + one cross-half shfl
    float pm = sc[0];
#pragma unroll
    for (int r = 1; r < 16; ++r) pm = fmaxf(pm, sc[r]);
    pm = fmaxf(pm, xhalf(pm));

    // ---- defer-max rescale (T13, THR=8 in base-2 units); guarded exp2
    if (!__all(pm <= m + 8.f)) {
      const float mn = fmaxf(m, pm);
      const float al = exp2f(fmaxf(m - mn, -80.f));   // guard -inf - -inf
#pragma unroll
      for (int r = 0; r < 16; ++r) { o0[r] *= al; o1[r] *= al; }
      lsum *= al;
      m = mn;
    }

    // ---- P = exp2(S - m), row sum
    float p[16];
    float rs = 0.f;
#pragma unroll
    for (int r = 0; r < 16; ++r) { p[r] = exp2f(sc[r] - m); rs += p[r]; }
    rs += xhalf(rs);
    lsum += rs;

    // ---- P -> PV B-frags: cvtpk + shfl + half-select
    u32 wl0 = cvtpk(p[0], p[1]),  wl1 = cvtpk(p[2], p[3]);
    u32 wh0 = cvtpk(p[4], p[5]),  wh1 = cvtpk(p[6], p[7]);
    u32 yl0 = cvtpk(p[8], p[9]),  yl1 = cvtpk(p[10], p[11]);
    u32 yh0 = cvtpk(p[12], p[13]), yh1 = cvtpk(p[14], p[15]);
    u32 sl0 = xhalfu(wl0), sl1 = xhalfu(wl1);
    u32 sh0 = xhalfu(wh0), sh1 = xhalfu(wh1);
    u32 tl0 = xhalfu(yl0), tl1 = xhalfu(yl1);
    u32 th0 = xhalfu(yh0), th1 = xhalfu(yh1);
    union { u32 w4[4]; bf16x8 v; } pf0, pf1;
    pf0.w4[0] = isHi ? sh0 : wl0;
    pf0.w4[1] = isHi ? sh1 : wl1;
    pf0.w4[2] = isHi ? wh0 : sl0;
    pf0.w4[3] = isHi ? wh1 : sl1;
    pf1.w4[0] = isHi ? th0 : yl0;
    pf1.w4[1] = isHi ? th1 : yl1;
    pf1.w4[2] = isHi ? yh0 : tl0;
    pf1.w4[3] = isHi ? yh1 : tl1;

    // ---- O^T += V^T P (rows=d, cols=q)
    __builtin_amdgcn_s_setprio(1);
    o0 = MFMA32(vf[0], pf0.v, o0, 0, 0, 0);
    o0 = MFMA32(vf[1], pf1.v, o0, 0, 0, 0);
    o1 = MFMA32(vf[2], pf0.v, o1, 0, 0, 0);
    o1 = MFMA32(vf[3], pf1.v, o1, 0, 0, 0);
    __builtin_amdgcn_s_setprio(0);
  };

  // main loop: 2x unrolled, double-buffered K/V fragments
  int u = s;
  if (u < e) loadKV(kA, vA, u);
  while (u < e) {
    if (u + 1 < e) loadKV(kB, vB, u + 1);
    compute(kA, vA, u);
    ++u;
    if (u >= e) break;
    if (u + 1 < e) loadKV(kA, vA, u + 1);
    compute(kB, vB, u);
    ++u;
  }

  // ---- combine: waves 1..3 publish, wave 0 merges
  if (w > 0) {
    float* dst = &shC[w - 1][l][0];
    dst[0] = m; dst[1] = lsum;
#pragma unroll
    for (int r = 0; r < 16; ++r) { dst[2 + r] = o0[r]; dst[18 + r] = o1[r]; }
  }
  __syncthreads();
  if (w == 0) {
#pragma unroll
    for (int peer = 0; peer < 3; ++peer) {
      const float* src = &shC[peer][l][0];
      const float pm = src[0], pl = src[1];
      const float mn = fmaxf(m, pm);
      const float aS = exp2f(fmaxf(m - mn, -80.f));   // NaN(-inf - -inf) -> -80 guard
      const float aP = exp2f(fmaxf(pm - mn, -80.f));
      m = mn;
      lsum = lsum * aS + pl * aP;
#pragma unroll
      for (int r = 0; r < 16; ++r) {
        o0[r] = o0[r] * aS + src[2 + r] * aP;
        o1[r] = o1[r] * aS + src[18 + r] * aP;
      }
    }
    const float inv = 1.0f / lsum;
    // stage O (rows=q, cols=d) into LDS for coalesced output
#pragma unroll
    for (int r = 0; r < 16; ++r) {
      const int d = (r & 3) + 8 * (r >> 2) + 4 * hi;
      shT[q][d] = o0[r] * inv;
      shT[q][32 + d] = o1[r] * inv;
    }
    __asm volatile("s_waitcnt lgkmcnt(0)" ::: "memory");  // same-wave LDS RAW
#pragma unroll
    for (int it = 0; it < 8; ++it) {
      const int row = it * 4 + (l >> 4);
      const int c4 = (l & 15) * 4;
      float4 v = *(const float4*)&shT[row][c4];
      *(float4*)(out + (size_t)(bT + q0 + row) * 64 + c4) = v;
    }
  }
}

extern "C" void kernel_launch(void* const* d_in, const int* in_sizes, int n_in,
                              void* d_out, int out_size, void* d_ws, size_t ws_size,
                              hipStream_t stream) {
  const float* x  = (const float*)d_in[0];
  const float* Wq = (const float*)d_in[1];
  const float* Wk = (const float*)d_in[2];
  const float* Wv = (const float*)d_in[3];
  float* out = (float*)d_out;

  char* ws = (char*)d_ws;
  u16* Wt = (u16*)ws;                                   // 192*1024*2   = 384 KiB
  u16* Qb = (u16*)(ws + 393216);                        // 16384*64*2   = 2 MiB
  u16* Kb = (u16*)(ws + 393216 + 2097152);
  u16* Vt = (u16*)(ws + 393216 + 2 * 2097152);          // transposed V [64][16384]

  wt_kernel<<<192, 256, 0, stream>>>(Wq, Wk, Wv, Wt);
  qkv6<<<512, 256, 0, stream>>>(x, Wt, Qb, Kb, Vt);
  attn4<<<512, 256, 0, stream>>>(Qb, Kb, Vt, out);
}